// Round 9
// baseline (191.949 us; speedup 1.0000x reference)
//
#include <hip/hip_runtime.h>
#include <hip/hip_bf16.h>

#define N_NODES 50000
#define N_EDGES 800000
#define N_GRAPHS 128
#define IN_CH 16
#define HIDDEN 64
#define OUT_CH 2

// ---- bucket-sort CSR build params ----
#define BSHIFT 7
#define BNODES 128                               // nodes per bucket
#define NB ((N_NODES + BNODES - 1) / BNODES)     // 391 buckets
#define ECHUNK 4096                              // edges per S1/S3 block (256 thr x 16)
#define EB ((N_EDGES + ECHUNK - 1) / ECHUNK)     // 196 edge blocks
#define SLEN (NB * EB)                           // 76636 scan entries
#define SCHUNK 1024                              // scan entries per block (256 thr x 4)
#define NSB ((SLEN + SCHUNK - 1) / SCHUNK)       // 75 (<= 256)
#define MAXK 12                                  // bucket_csr edges/thread cap (3072/bucket)
#define WT2_LD 66                                // W2^T stride: bank=(2c+k)%32 -> 2-way (free)
#define WT1_LD 18                                // W1^T stride: same property

__device__ __forceinline__ float bf2f(unsigned short u) {
    return __uint_as_float(((unsigned)u) << 16);
}

// ---------------- CSR build: LDS bucket sort (no global returning atomics) ----------------

__global__ void bucket_hist_kernel(const int* __restrict__ dst, int* __restrict__ bh,
                                   float* __restrict__ sums, float* __restrict__ cntg) {
    __shared__ int lh[NB];
    int t = threadIdx.x;
    if (blockIdx.x == 0) {
        for (int i = t; i < N_GRAPHS * HIDDEN; i += 256) sums[i] = 0.0f;
        if (t < N_GRAPHS) cntg[t] = 0.0f;
    }
    for (int i = t; i < NB; i += 256) lh[i] = 0;
    __syncthreads();
    int base = blockIdx.x * ECHUNK;
    for (int i = t; i < ECHUNK; i += 256) {
        int e = base + i;
        if (e < N_EDGES) {
            int d = dst[e];
            if ((unsigned)d < N_NODES) atomicAdd(&lh[d >> BSHIFT], 1);
        }
    }
    __syncthreads();
    for (int i = t; i < NB; i += 256) bh[i * EB + blockIdx.x] = lh[i];
}

__global__ void scan_part_kernel(const int* __restrict__ a, int* __restrict__ bsum) {
    __shared__ int s[256];
    int t = threadIdx.x;
    int ebase = blockIdx.x * SCHUNK + t * 4;
    int v = 0;
    if (ebase + 3 < SLEN) {
        int4 c = *(const int4*)&a[ebase];
        v = c.x + c.y + c.z + c.w;
    } else {
        for (int k = 0; k < 4; k++) {
            int i = ebase + k;
            if (i < SLEN) v += a[i];
        }
    }
    s[t] = v;
    __syncthreads();
    for (int off = 128; off > 0; off >>= 1) {
        if (t < off) s[t] += s[t + off];
        __syncthreads();
    }
    if (t == 0) bsum[blockIdx.x] = s[0];
}

__global__ void scan_apply_kernel(const int* __restrict__ a, const int* __restrict__ bsum,
                                  int* __restrict__ boff) {
    __shared__ int sb[256];
    __shared__ int st[256];
    int t = threadIdx.x;
    sb[t] = (t < NSB) ? bsum[t] : 0;
    __syncthreads();
    for (int off = 1; off < 256; off <<= 1) {
        int u = (t >= off) ? sb[t - off] : 0;
        __syncthreads();
        sb[t] += u;
        __syncthreads();
    }
    int blockOff = (blockIdx.x > 0) ? sb[blockIdx.x - 1] : 0;

    int ebase = blockIdx.x * SCHUNK + t * 4;
    int c0 = 0, c1 = 0, c2 = 0, c3 = 0;
    bool full = (ebase + 3 < SLEN);
    if (full) {
        int4 c = *(const int4*)&a[ebase];
        c0 = c.x; c1 = c.y; c2 = c.z; c3 = c.w;
    } else {
        if (ebase < SLEN) c0 = a[ebase];
        if (ebase + 1 < SLEN) c1 = a[ebase + 1];
        if (ebase + 2 < SLEN) c2 = a[ebase + 2];
    }
    int tsum = c0 + c1 + c2 + c3;
    st[t] = tsum;
    __syncthreads();
    for (int off = 1; off < 256; off <<= 1) {
        int u = (t >= off) ? st[t - off] : 0;
        __syncthreads();
        st[t] += u;
        __syncthreads();
    }
    int p = blockOff + st[t] - tsum;
    if (full) {
        int4 o;
        o.x = p; o.y = p + c0; o.z = p + c0 + c1; o.w = p + c0 + c1 + c2;
        *(int4*)&boff[ebase] = o;
    } else {
        if (ebase < SLEN) boff[ebase] = p;
        if (ebase + 1 < SLEN) boff[ebase + 1] = p + c0;
        if (ebase + 2 < SLEN) boff[ebase + 2] = p + c0 + c1;
        if (ebase + 3 < SLEN) boff[ebase + 3] = p + c0 + c1 + c2;
    }
}

__global__ void bucket_scatter_kernel(const int* __restrict__ src, const int* __restrict__ dst,
                                      const int* __restrict__ boff, int2* __restrict__ pairs) {
    __shared__ int lcnt[NB];
    __shared__ int goff[NB];
    int t = threadIdx.x;
    for (int i = t; i < NB; i += 256) {
        lcnt[i] = 0;
        goff[i] = boff[i * EB + blockIdx.x];
    }
    __syncthreads();
    int base = blockIdx.x * ECHUNK;
    for (int i = t; i < ECHUNK; i += 256) {
        int e = base + i;
        if (e < N_EDGES) {
            int d = dst[e];
            if ((unsigned)d < N_NODES) {
                int b = d >> BSHIFT;
                int r = atomicAdd(&lcnt[b], 1);
                int2 p;
                p.x = src[e];
                p.y = d;
                pairs[goff[b] + r] = p;
            }
        }
    }
}

__global__ void bucket_csr_kernel(const int2* __restrict__ pairs, const int* __restrict__ boff,
                                  int* __restrict__ csr, int* __restrict__ rowptr,
                                  int* __restrict__ cnt_node, float* __restrict__ dinv) {
    __shared__ int lcnt[BNODES];
    __shared__ int ls[BNODES];
    __shared__ int lrow[BNODES];
    int b = blockIdx.x;
    int t = threadIdx.x;
    if (t < BNODES) lcnt[t] = 0;
    __syncthreads();
    int bstart = boff[b * EB];
    int bend = (b + 1 < NB) ? boff[(b + 1) * EB] : N_EDGES;
    int K = bend - bstart;
    int myn[MAXK], myr[MAXK], mys[MAXK];
#pragma unroll
    for (int k = 0; k < MAXK; k++) {
        int i = k * 256 + t;
        if (i < K) {
            int2 p = pairs[bstart + i];
            int nl = p.y & (BNODES - 1);
            mys[k] = p.x;
            myn[k] = nl;
            myr[k] = atomicAdd(&lcnt[nl], 1);
        }
    }
    __syncthreads();
    if (t < BNODES) ls[t] = lcnt[t];
    __syncthreads();
    for (int off = 1; off < BNODES; off <<= 1) {
        int u = (t >= off && t < BNODES) ? ls[t - off] : 0;
        __syncthreads();
        if (t < BNODES) ls[t] += u;
        __syncthreads();
    }
    if (t < BNODES) {
        int ex = ls[t] - lcnt[t];
        lrow[t] = ex;
        int n = b * BNODES + t;
        if (n < N_NODES) {
            rowptr[n] = bstart + ex;
            cnt_node[n] = lcnt[t];
            dinv[n] = rsqrtf((float)(lcnt[t] + 1));  // +1 self-loop
        }
    }
    __syncthreads();
#pragma unroll
    for (int k = 0; k < MAXK; k++) {
        int i = k * 256 + t;
        if (i < K) csr[bstart + lrow[myn[k]] + myr[k]] = mys[k];
    }
}

// ---------------- fused layer 1: aggregate(x) -> LDS -> linear+relu -> h1' (bf16, pre-scaled) ----------------

// Phase A: 4 lanes/edge, float4 per lane; 4 rows per wave INTERLEAVED (16 gathers in flight).
// Phase B: W1^T stride 18 (2-way banks, free), float2 reads. Output h1' = dinv[n]*relu(.).
__global__ void fused_l1_kernel(const float* __restrict__ x, const int* __restrict__ csr_src,
                                const int* __restrict__ rowptr, const int* __restrict__ cnt,
                                const float* __restrict__ dinv, const float* __restrict__ W,
                                const float* __restrict__ b, __hip_bfloat16* __restrict__ h) {
    __shared__ float sWT[HIDDEN * WT1_LD];   // 4.6 KB
    __shared__ float sx[16 * IN_CH];         // 1 KB
    int t = threadIdx.x;
    for (int i = t; i < IN_CH * HIDDEN; i += 256) {
        int k = i >> 6, c = i & 63;
        sWT[c * WT1_LD + k] = W[i];
    }

    int n0 = blockIdx.x * 16;
    int w = t >> 6;
    int lane = t & 63;
    int e16 = lane >> 2;          // edge slot 0..15
    int cc = (lane & 3) * 4;      // channel quad

    int len[4], start[4];
    float4 acc[4];
    int maxlen = 0;
#pragma unroll
    for (int q = 0; q < 4; q++) {
        int n = n0 + w * 4 + q;
        bool valid = n < N_NODES;
        len[q] = valid ? cnt[n] : 0;
        start[q] = valid ? rowptr[n] : 0;
        if (len[q] > maxlen) maxlen = len[q];
        acc[q] = make_float4(0.f, 0.f, 0.f, 0.f);
    }
    for (int i = e16; i < maxlen; i += 16) {
#pragma unroll
        for (int q = 0; q < 4; q++) {
            if (i < len[q]) {
                int s = csr_src[start[q] + i];
                float dv = dinv[s];
                float4 xv = *(const float4*)&x[s * IN_CH + cc];
                acc[q].x += dv * xv.x; acc[q].y += dv * xv.y;
                acc[q].z += dv * xv.z; acc[q].w += dv * xv.w;
            }
        }
    }
#pragma unroll
    for (int q = 0; q < 4; q++) {
#pragma unroll
        for (int m = 4; m <= 32; m <<= 1) {
            acc[q].x += __shfl_xor(acc[q].x, m, 64);
            acc[q].y += __shfl_xor(acc[q].y, m, 64);
            acc[q].z += __shfl_xor(acc[q].z, m, 64);
            acc[q].w += __shfl_xor(acc[q].w, m, 64);
        }
        int row = w * 4 + q;
        int n = n0 + row;
        if (lane < 4 && n < N_NODES) {
            float dn = dinv[n];
            float4 xs = *(const float4*)&x[n * IN_CH + cc];
            float4 v;
            v.x = dn * acc[q].x + dn * dn * xs.x;
            v.y = dn * acc[q].y + dn * dn * xs.y;
            v.z = dn * acc[q].z + dn * dn * xs.z;
            v.w = dn * acc[q].w + dn * dn * xs.w;
            *(float4*)&sx[row * IN_CH + cc] = v;
        }
    }
    __syncthreads();

    int r = w;
    int c = t & 63;
    float bias = b[c];
#pragma unroll
    for (int nb = 0; nb < 4; nb++) {
        int row = nb * 4 + r;
        int n = n0 + row;
        if (n >= N_NODES) continue;
        float acch = bias;
#pragma unroll
        for (int k4 = 0; k4 < IN_CH; k4 += 4) {
            float4 a = *(const float4*)&sx[row * IN_CH + k4];
            float2 w0 = *(const float2*)&sWT[c * WT1_LD + k4];
            float2 w1 = *(const float2*)&sWT[c * WT1_LD + k4 + 2];
            acch += a.x * w0.x + a.y * w0.y + a.z * w1.x + a.w * w1.y;
        }
        float v = acch > 0.0f ? acch : 0.0f;
        h[n * HIDDEN + c] = __float2bfloat16(dinv[n] * v);   // pre-scaled h1'
    }
}

// ---------------- fused layer 2: aggregate(h1') -> LDS -> linear+relu -> pool ----------------

// Phase A: 16 lanes/edge, ushort4 per lane; 4 rows per wave INTERLEAVED (16 gathers in flight).
// agg = dn * (sum_s h1'[s] + h1'[n])  -- no per-edge dinv.
// Phase B: W2^T stride 66 (2-way banks, free), float2 reads.
__global__ void fused_l2_kernel(const __hip_bfloat16* __restrict__ h, const int* __restrict__ csr_src,
                                const int* __restrict__ rowptr, const int* __restrict__ cnt,
                                const float* __restrict__ dinv, const float* __restrict__ W,
                                const float* __restrict__ b, const int* __restrict__ batch,
                                float* __restrict__ sums, float* __restrict__ cntg) {
    __shared__ float sWT[HIDDEN * WT2_LD];  // 16.5 KB
    __shared__ float sagg[16 * HIDDEN];     // 4 KB
    __shared__ float sred[4 * HIDDEN];      // 1 KB
    int t = threadIdx.x;
    for (int i = t; i < HIDDEN * HIDDEN; i += 256) {
        int k = i >> 6, c = i & 63;
        sWT[c * WT2_LD + k] = W[i];
    }

    int n0 = blockIdx.x * 16;
    int w = t >> 6;
    int lane = t & 63;
    int e4 = lane >> 4;          // edge slot 0..3
    int cc = (lane & 15) * 4;    // channel quad
    const unsigned short* hu = (const unsigned short*)h;

    int len[4], start[4];
    float4 acc[4];
    int maxlen = 0;
#pragma unroll
    for (int q = 0; q < 4; q++) {
        int n = n0 + w * 4 + q;
        bool valid = n < N_NODES;
        len[q] = valid ? cnt[n] : 0;
        start[q] = valid ? rowptr[n] : 0;
        if (len[q] > maxlen) maxlen = len[q];
        acc[q] = make_float4(0.f, 0.f, 0.f, 0.f);
    }
    for (int i = e4; i < maxlen; i += 4) {
#pragma unroll
        for (int q = 0; q < 4; q++) {
            if (i < len[q]) {
                int s = csr_src[start[q] + i];
                ushort4 a = *(const ushort4*)&hu[s * HIDDEN + cc];
                acc[q].x += bf2f(a.x);
                acc[q].y += bf2f(a.y);
                acc[q].z += bf2f(a.z);
                acc[q].w += bf2f(a.w);
            }
        }
    }
#pragma unroll
    for (int q = 0; q < 4; q++) {
        acc[q].x += __shfl_xor(acc[q].x, 16, 64);
        acc[q].y += __shfl_xor(acc[q].y, 16, 64);
        acc[q].z += __shfl_xor(acc[q].z, 16, 64);
        acc[q].w += __shfl_xor(acc[q].w, 16, 64);
        acc[q].x += __shfl_xor(acc[q].x, 32, 64);
        acc[q].y += __shfl_xor(acc[q].y, 32, 64);
        acc[q].z += __shfl_xor(acc[q].z, 32, 64);
        acc[q].w += __shfl_xor(acc[q].w, 32, 64);
        int row = w * 4 + q;
        int n = n0 + row;
        if (lane < 16 && n < N_NODES) {
            ushort4 sv = *(const ushort4*)&hu[n * HIDDEN + cc];
            float dn = dinv[n];
            float4 v;
            v.x = dn * (acc[q].x + bf2f(sv.x));
            v.y = dn * (acc[q].y + bf2f(sv.y));
            v.z = dn * (acc[q].z + bf2f(sv.z));
            v.w = dn * (acc[q].w + bf2f(sv.w));
            *(float4*)&sagg[row * HIDDEN + cc] = v;
        }
    }
    __syncthreads();

    // Phase B: gemm2 + bias + relu
    int r = w;
    int c = t & 63;
    float bias = b[c];
    float vout[4];
#pragma unroll
    for (int nb = 0; nb < 4; nb++) {
        int row = nb * 4 + r;
        int n = n0 + row;
        vout[nb] = 0.0f;
        if (n >= N_NODES) continue;
        float acch = bias;
#pragma unroll
        for (int k4 = 0; k4 < HIDDEN; k4 += 4) {
            float4 a = *(const float4*)&sagg[row * HIDDEN + k4];
            float2 w0 = *(const float2*)&sWT[c * WT2_LD + k4];
            float2 w1 = *(const float2*)&sWT[c * WT2_LD + k4 + 2];
            acch += a.x * w0.x + a.y * w0.y + a.z * w1.x + a.w * w1.y;
        }
        vout[nb] = acch > 0.0f ? acch : 0.0f;
    }
    __syncthreads();

#pragma unroll
    for (int nb = 0; nb < 4; nb++) {
        int row = nb * 4 + r;
        if (n0 + row < N_NODES) sagg[row * HIDDEN + c] = vout[nb];
    }
    __syncthreads();

    // Phase C: pool (batch sorted -> tile usually one graph)
    int nlast = n0 + 15;
    if (nlast >= N_NODES) nlast = N_NODES - 1;
    int glo = batch[n0];
    int ghi = batch[nlast];
    if (glo == ghi) {
        float p = 0.0f;
#pragma unroll
        for (int q = 0; q < 4; q++) {
            int row = 4 * r + q;
            if (n0 + row < N_NODES) p += sagg[row * HIDDEN + c];
        }
        sred[r * HIDDEN + c] = p;
        __syncthreads();
        if (r == 0) {
            float v = sred[c] + sred[HIDDEN + c] + sred[2 * HIDDEN + c] + sred[3 * HIDDEN + c];
            atomicAdd(&sums[glo * HIDDEN + c], v);
            if (c == 0) atomicAdd(&cntg[glo], (float)(nlast - n0 + 1));
        }
    } else {
        int gcur = -1;
        float acch = 0.0f, ccnt = 0.0f;
        for (int q = 0; q < 4; q++) {
            int row = 4 * r + q;
            int n = n0 + row;
            if (n >= N_NODES) break;
            int g = batch[n];
            if ((unsigned)g >= N_GRAPHS) continue;
            if (g != gcur) {
                if (gcur >= 0) {
                    atomicAdd(&sums[gcur * HIDDEN + c], acch);
                    if (c == 0) atomicAdd(&cntg[gcur], ccnt);
                }
                gcur = g;
                acch = 0.0f;
                ccnt = 0.0f;
            }
            acch += sagg[row * HIDDEN + c];
            ccnt += 1.0f;
        }
        if (gcur >= 0) {
            atomicAdd(&sums[gcur * HIDDEN + c], acch);
            if (c == 0) atomicAdd(&cntg[gcur], ccnt);
        }
    }
}

// ---------------- head ----------------

__global__ void head_kernel(const float* __restrict__ sums, const float* __restrict__ cntg,
                            const float* __restrict__ Wc, const float* __restrict__ bc,
                            float* __restrict__ out) {
    int t = blockIdx.x * blockDim.x + threadIdx.x;
    if (t >= N_GRAPHS * OUT_CH) return;
    int g = t >> 1;
    int o = t & 1;
    float inv = 1.0f / fmaxf(cntg[g], 1.0f);
    float acc = bc[o];
#pragma unroll
    for (int k = 0; k < HIDDEN; k++) acc += sums[g * HIDDEN + k] * inv * Wc[k * OUT_CH + o];
    out[t] = acc;
}

// ---------------- launch ----------------

extern "C" void kernel_launch(void* const* d_in, const int* in_sizes, int n_in,
                              void* d_out, int out_size, void* d_ws, size_t ws_size,
                              hipStream_t stream) {
    const float* x  = (const float*)d_in[0];
    const int* ei   = (const int*)d_in[1];
    const int* bat  = (const int*)d_in[2];
    const float* W1 = (const float*)d_in[3];
    const float* b1 = (const float*)d_in[4];
    const float* W2 = (const float*)d_in[5];
    const float* b2 = (const float*)d_in[6];
    const float* Wc = (const float*)d_in[7];
    const float* bc = (const float*)d_in[8];
    float* out = (float*)d_out;

    const int* src = ei;
    const int* dst = ei + N_EDGES;

    char* ws = (char*)d_ws;
    size_t off = 0;
    auto carve = [&](size_t nbytes) {
        char* p = ws + off;
        off += (nbytes + 255) & ~(size_t)255;
        return p;
    };
    float* sums     = (float*)carve(N_GRAPHS * HIDDEN * sizeof(float));
    float* cntg     = (float*)carve(N_GRAPHS * sizeof(float));
    int*   bh       = (int*)carve((size_t)SLEN * sizeof(int));
    int*   bsum     = (int*)carve(NSB * sizeof(int));
    int*   boff     = (int*)carve((size_t)SLEN * sizeof(int));
    int2*  pairs    = (int2*)carve((size_t)N_EDGES * sizeof(int2));
    int*   csr      = (int*)carve((size_t)N_EDGES * sizeof(int));
    int*   rowptr   = (int*)carve(N_NODES * sizeof(int));
    int*   cnt_node = (int*)carve(N_NODES * sizeof(int));
    float* dinv     = (float*)carve(N_NODES * sizeof(float));
    __hip_bfloat16* bufA = (__hip_bfloat16*)carve((size_t)N_NODES * HIDDEN * sizeof(__hip_bfloat16));
    (void)ws_size;

    const int node16Blk = (N_NODES + 15) / 16;

    bucket_hist_kernel<<<EB, 256, 0, stream>>>(dst, bh, sums, cntg);
    scan_part_kernel<<<NSB, 256, 0, stream>>>(bh, bsum);
    scan_apply_kernel<<<NSB, 256, 0, stream>>>(bh, bsum, boff);
    bucket_scatter_kernel<<<EB, 256, 0, stream>>>(src, dst, boff, pairs);
    bucket_csr_kernel<<<NB, 256, 0, stream>>>(pairs, boff, csr, rowptr, cnt_node, dinv);

    fused_l1_kernel<<<node16Blk, 256, 0, stream>>>(x, csr, rowptr, cnt_node, dinv, W1, b1, bufA);
    fused_l2_kernel<<<node16Blk, 256, 0, stream>>>(bufA, csr, rowptr, cnt_node, dinv, W2, b2,
                                                   bat, sums, cntg);
    head_kernel<<<1, 256, 0, stream>>>(sums, cntg, Wc, bc, out);
}

// Round 10
// 178.069 us; speedup vs baseline: 1.0779x; 1.0779x over previous
//
#include <hip/hip_runtime.h>
#include <hip/hip_bf16.h>

#define N_NODES 50000
#define N_EDGES 800000
#define N_GRAPHS 128
#define IN_CH 16
#define HIDDEN 64
#define OUT_CH 2

// ---- bucket-sort CSR build params ----
#define BSHIFT 7
#define BNODES 128
#define NB ((N_NODES + BNODES - 1) / BNODES)     // 391 buckets
#define ECHUNK 4096
#define EB ((N_EDGES + ECHUNK - 1) / ECHUNK)     // 196 edge blocks
#define SLEN (NB * EB)                           // 76636 scan entries
#define SCHUNK 1024
#define NSB ((SLEN + SCHUNK - 1) / SCHUNK)       // 75 (<= 256)
#define MAXK 12
#define WT1_LD 18                                // W1^T stride: 2-way banks (free)
#define AGG_LD 72                                // bf16 LDS stride: b128 frag reads uniform over banks

typedef __attribute__((ext_vector_type(8))) short bf16x8;
typedef __attribute__((ext_vector_type(4))) float f32x4;

__device__ __forceinline__ float bf2f(unsigned short u) {
    return __uint_as_float(((unsigned)u) << 16);
}
__device__ __forceinline__ unsigned short f2bf(float f) {
    __hip_bfloat16 h = __float2bfloat16(f);
    return *reinterpret_cast<unsigned short*>(&h);
}

// ---------------- CSR build: LDS bucket sort (no global returning atomics) ----------------

__global__ void bucket_hist_kernel(const int* __restrict__ dst, int* __restrict__ bh,
                                   float* __restrict__ sums, float* __restrict__ cntg) {
    __shared__ int lh[NB];
    int t = threadIdx.x;
    if (blockIdx.x == 0) {
        for (int i = t; i < N_GRAPHS * HIDDEN; i += 256) sums[i] = 0.0f;
        if (t < N_GRAPHS) cntg[t] = 0.0f;
    }
    for (int i = t; i < NB; i += 256) lh[i] = 0;
    __syncthreads();
    int base = blockIdx.x * ECHUNK;
    for (int i = t; i < ECHUNK; i += 256) {
        int e = base + i;
        if (e < N_EDGES) {
            int d = dst[e];
            if ((unsigned)d < N_NODES) atomicAdd(&lh[d >> BSHIFT], 1);
        }
    }
    __syncthreads();
    for (int i = t; i < NB; i += 256) bh[i * EB + blockIdx.x] = lh[i];
}

__global__ void scan_part_kernel(const int* __restrict__ a, int* __restrict__ bsum) {
    __shared__ int s[256];
    int t = threadIdx.x;
    int ebase = blockIdx.x * SCHUNK + t * 4;
    int v = 0;
    if (ebase + 3 < SLEN) {
        int4 c = *(const int4*)&a[ebase];
        v = c.x + c.y + c.z + c.w;
    } else {
        for (int k = 0; k < 4; k++) {
            int i = ebase + k;
            if (i < SLEN) v += a[i];
        }
    }
    s[t] = v;
    __syncthreads();
    for (int off = 128; off > 0; off >>= 1) {
        if (t < off) s[t] += s[t + off];
        __syncthreads();
    }
    if (t == 0) bsum[blockIdx.x] = s[0];
}

__global__ void scan_apply_kernel(const int* __restrict__ a, const int* __restrict__ bsum,
                                  int* __restrict__ boff) {
    __shared__ int sb[256];
    __shared__ int st[256];
    int t = threadIdx.x;
    sb[t] = (t < NSB) ? bsum[t] : 0;
    __syncthreads();
    for (int off = 1; off < 256; off <<= 1) {
        int u = (t >= off) ? sb[t - off] : 0;
        __syncthreads();
        sb[t] += u;
        __syncthreads();
    }
    int blockOff = (blockIdx.x > 0) ? sb[blockIdx.x - 1] : 0;

    int ebase = blockIdx.x * SCHUNK + t * 4;
    int c0 = 0, c1 = 0, c2 = 0, c3 = 0;
    bool full = (ebase + 3 < SLEN);
    if (full) {
        int4 c = *(const int4*)&a[ebase];
        c0 = c.x; c1 = c.y; c2 = c.z; c3 = c.w;
    } else {
        if (ebase < SLEN) c0 = a[ebase];
        if (ebase + 1 < SLEN) c1 = a[ebase + 1];
        if (ebase + 2 < SLEN) c2 = a[ebase + 2];
    }
    int tsum = c0 + c1 + c2 + c3;
    st[t] = tsum;
    __syncthreads();
    for (int off = 1; off < 256; off <<= 1) {
        int u = (t >= off) ? st[t - off] : 0;
        __syncthreads();
        st[t] += u;
        __syncthreads();
    }
    int p = blockOff + st[t] - tsum;
    if (full) {
        int4 o;
        o.x = p; o.y = p + c0; o.z = p + c0 + c1; o.w = p + c0 + c1 + c2;
        *(int4*)&boff[ebase] = o;
    } else {
        if (ebase < SLEN) boff[ebase] = p;
        if (ebase + 1 < SLEN) boff[ebase + 1] = p + c0;
        if (ebase + 2 < SLEN) boff[ebase + 2] = p + c0 + c1;
        if (ebase + 3 < SLEN) boff[ebase + 3] = p + c0 + c1 + c2;
    }
}

__global__ void bucket_scatter_kernel(const int* __restrict__ src, const int* __restrict__ dst,
                                      const int* __restrict__ boff, int2* __restrict__ pairs) {
    __shared__ int lcnt[NB];
    __shared__ int goff[NB];
    int t = threadIdx.x;
    for (int i = t; i < NB; i += 256) {
        lcnt[i] = 0;
        goff[i] = boff[i * EB + blockIdx.x];
    }
    __syncthreads();
    int base = blockIdx.x * ECHUNK;
    for (int i = t; i < ECHUNK; i += 256) {
        int e = base + i;
        if (e < N_EDGES) {
            int d = dst[e];
            if ((unsigned)d < N_NODES) {
                int b = d >> BSHIFT;
                int r = atomicAdd(&lcnt[b], 1);
                int2 p;
                p.x = src[e];
                p.y = d;
                pairs[goff[b] + r] = p;
            }
        }
    }
}

__global__ void bucket_csr_kernel(const int2* __restrict__ pairs, const int* __restrict__ boff,
                                  int* __restrict__ csr, int* __restrict__ rowptr,
                                  int* __restrict__ cnt_node, float* __restrict__ dinv) {
    __shared__ int lcnt[BNODES];
    __shared__ int ls[BNODES];
    __shared__ int lrow[BNODES];
    int b = blockIdx.x;
    int t = threadIdx.x;
    if (t < BNODES) lcnt[t] = 0;
    __syncthreads();
    int bstart = boff[b * EB];
    int bend = (b + 1 < NB) ? boff[(b + 1) * EB] : N_EDGES;
    int K = bend - bstart;
    int myn[MAXK], myr[MAXK], mys[MAXK];
#pragma unroll
    for (int k = 0; k < MAXK; k++) {
        int i = k * 256 + t;
        if (i < K) {
            int2 p = pairs[bstart + i];
            int nl = p.y & (BNODES - 1);
            mys[k] = p.x;
            myn[k] = nl;
            myr[k] = atomicAdd(&lcnt[nl], 1);
        }
    }
    __syncthreads();
    if (t < BNODES) ls[t] = lcnt[t];
    __syncthreads();
    for (int off = 1; off < BNODES; off <<= 1) {
        int u = (t >= off && t < BNODES) ? ls[t - off] : 0;
        __syncthreads();
        if (t < BNODES) ls[t] += u;
        __syncthreads();
    }
    if (t < BNODES) {
        int ex = ls[t] - lcnt[t];
        lrow[t] = ex;
        int n = b * BNODES + t;
        if (n < N_NODES) {
            rowptr[n] = bstart + ex;
            cnt_node[n] = lcnt[t];
            dinv[n] = rsqrtf((float)(lcnt[t] + 1));  // +1 self-loop
        }
    }
    __syncthreads();
#pragma unroll
    for (int k = 0; k < MAXK; k++) {
        int i = k * 256 + t;
        if (i < K) csr[bstart + lrow[myn[k]] + myr[k]] = mys[k];
    }
}

// ---------------- fused layer 1: aggregate(x) -> LDS -> linear+relu -> h1' (bf16, pre-scaled) ----------------

// Phase A: serial rows, 4 lanes/edge, float4 per lane (16 edges per wave-instr).
// Phase B: W1^T stride 18 (2-way banks, free). Output h1' = dinv[n]*relu(.).
__global__ void fused_l1_kernel(const float* __restrict__ x, const int* __restrict__ csr_src,
                                const int* __restrict__ rowptr, const int* __restrict__ cnt,
                                const float* __restrict__ dinv, const float* __restrict__ W,
                                const float* __restrict__ b, __hip_bfloat16* __restrict__ h) {
    __shared__ float sWT[HIDDEN * WT1_LD];   // 4.6 KB
    __shared__ float sx[16 * IN_CH];         // 1 KB
    int t = threadIdx.x;
    for (int i = t; i < IN_CH * HIDDEN; i += 256) {
        int k = i >> 6, c = i & 63;
        sWT[c * WT1_LD + k] = W[i];
    }

    int n0 = blockIdx.x * 16;
    int w = t >> 6;
    int lane = t & 63;
    int e16 = lane >> 2;          // edge slot 0..15
    int cc = (lane & 3) * 4;      // channel quad

    for (int q = 0; q < 4; q++) {
        int row = w * 4 + q;
        int n = n0 + row;
        if (n >= N_NODES) break;
        int len = cnt[n];
        int start = rowptr[n];
        float4 acc = make_float4(0.f, 0.f, 0.f, 0.f);
        for (int i = e16; i < len; i += 16) {
            int s = csr_src[start + i];
            float dv = dinv[s];
            float4 xv = *(const float4*)&x[s * IN_CH + cc];
            acc.x += dv * xv.x; acc.y += dv * xv.y;
            acc.z += dv * xv.z; acc.w += dv * xv.w;
        }
#pragma unroll
        for (int m = 4; m <= 32; m <<= 1) {
            acc.x += __shfl_xor(acc.x, m, 64);
            acc.y += __shfl_xor(acc.y, m, 64);
            acc.z += __shfl_xor(acc.z, m, 64);
            acc.w += __shfl_xor(acc.w, m, 64);
        }
        if (lane < 4) {
            float dn = dinv[n];
            float4 xs = *(const float4*)&x[n * IN_CH + cc];
            float4 v;
            v.x = dn * acc.x + dn * dn * xs.x;
            v.y = dn * acc.y + dn * dn * xs.y;
            v.z = dn * acc.z + dn * dn * xs.z;
            v.w = dn * acc.w + dn * dn * xs.w;
            *(float4*)&sx[row * IN_CH + cc] = v;
        }
    }
    __syncthreads();

    int r = w;
    int c = t & 63;
    float bias = b[c];
#pragma unroll
    for (int nb = 0; nb < 4; nb++) {
        int row = nb * 4 + r;
        int n = n0 + row;
        if (n >= N_NODES) continue;
        float acch = bias;
#pragma unroll
        for (int k4 = 0; k4 < IN_CH; k4 += 4) {
            float4 a = *(const float4*)&sx[row * IN_CH + k4];
            float2 w0 = *(const float2*)&sWT[c * WT1_LD + k4];
            float2 w1 = *(const float2*)&sWT[c * WT1_LD + k4 + 2];
            acch += a.x * w0.x + a.y * w0.y + a.z * w1.x + a.w * w1.y;
        }
        float v = acch > 0.0f ? acch : 0.0f;
        h[n * HIDDEN + c] = __float2bfloat16(dinv[n] * v);   // pre-scaled h1'
    }
}

// ---------------- fused layer 2: aggregate(h1') -> bf16 LDS -> MFMA gemm2 -> pool ----------------

// Phase A: serial rows, 16 lanes/edge, ushort4 per lane, 4-deep unroll.
// Phase B: two v_mfma_f32_16x16x32_bf16 per wave (16 nodes x 16 ch tile, K=64).
// Phase C: pool straight from MFMA C-layout (no LDS round-trip).
__global__ void fused_l2_kernel(const __hip_bfloat16* __restrict__ h, const int* __restrict__ csr_src,
                                const int* __restrict__ rowptr, const int* __restrict__ cnt,
                                const float* __restrict__ dinv, const float* __restrict__ W,
                                const float* __restrict__ b, const int* __restrict__ batch,
                                float* __restrict__ sums, float* __restrict__ cntg) {
    __shared__ unsigned short sW[HIDDEN * AGG_LD];   // W2^T bf16 [c][k], 9.2 KB
    __shared__ unsigned short sagg[16 * AGG_LD];     // agg bf16 [row][k], 2.3 KB
    int t = threadIdx.x;
    // stage W2^T as bf16 (one-time, 16 iters)
    for (int i = t; i < HIDDEN * HIDDEN; i += 256) {
        int k = i >> 6, c = i & 63;
        sW[c * AGG_LD + k] = f2bf(W[i]);
    }

    int n0 = blockIdx.x * 16;
    int w = t >> 6;
    int lane = t & 63;
    int e4 = lane >> 4;          // edge slot 0..3
    int cc = (lane & 15) * 4;    // channel quad
    const unsigned short* hu = (const unsigned short*)h;

    // Phase A: aggregate (rows serial, 4 gather instrs in flight per row)
    for (int q = 0; q < 4; q++) {
        int row = w * 4 + q;
        int n = n0 + row;
        int len = cnt[n];
        int start = rowptr[n];
        float4 acc = make_float4(0.f, 0.f, 0.f, 0.f);
        int i = e4;
        for (; i + 12 < len; i += 16) {
            int s0 = csr_src[start + i];
            int s1 = csr_src[start + i + 4];
            int s2 = csr_src[start + i + 8];
            int s3 = csr_src[start + i + 12];
            ushort4 a0 = *(const ushort4*)&hu[s0 * HIDDEN + cc];
            ushort4 a1 = *(const ushort4*)&hu[s1 * HIDDEN + cc];
            ushort4 a2 = *(const ushort4*)&hu[s2 * HIDDEN + cc];
            ushort4 a3 = *(const ushort4*)&hu[s3 * HIDDEN + cc];
            acc.x += (bf2f(a0.x) + bf2f(a1.x)) + (bf2f(a2.x) + bf2f(a3.x));
            acc.y += (bf2f(a0.y) + bf2f(a1.y)) + (bf2f(a2.y) + bf2f(a3.y));
            acc.z += (bf2f(a0.z) + bf2f(a1.z)) + (bf2f(a2.z) + bf2f(a3.z));
            acc.w += (bf2f(a0.w) + bf2f(a1.w)) + (bf2f(a2.w) + bf2f(a3.w));
        }
        for (; i < len; i += 4) {
            int s0 = csr_src[start + i];
            ushort4 a0 = *(const ushort4*)&hu[s0 * HIDDEN + cc];
            acc.x += bf2f(a0.x);
            acc.y += bf2f(a0.y);
            acc.z += bf2f(a0.z);
            acc.w += bf2f(a0.w);
        }
        acc.x += __shfl_xor(acc.x, 16, 64);
        acc.y += __shfl_xor(acc.y, 16, 64);
        acc.z += __shfl_xor(acc.z, 16, 64);
        acc.w += __shfl_xor(acc.w, 16, 64);
        acc.x += __shfl_xor(acc.x, 32, 64);
        acc.y += __shfl_xor(acc.y, 32, 64);
        acc.z += __shfl_xor(acc.z, 32, 64);
        acc.w += __shfl_xor(acc.w, 32, 64);
        if (lane < 16) {
            ushort4 sv = *(const ushort4*)&hu[n * HIDDEN + cc];
            float dn = dinv[n];
            ushort4 o;
            o.x = f2bf(dn * (acc.x + bf2f(sv.x)));
            o.y = f2bf(dn * (acc.y + bf2f(sv.y)));
            o.z = f2bf(dn * (acc.z + bf2f(sv.z)));
            o.w = f2bf(dn * (acc.w + bf2f(sv.w)));
            *(ushort4*)&sagg[row * AGG_LD + cc] = o;
        }
    }
    __syncthreads();

    // Phase B: MFMA. Wave w computes all 16 nodes x channels [16w, 16w+16).
    int quad = lane >> 4;
    int col = lane & 15;
    int cch = w * 16 + col;
    bf16x8 a0 = *(const bf16x8*)&sagg[col * AGG_LD + quad * 8];
    bf16x8 a1 = *(const bf16x8*)&sagg[col * AGG_LD + 32 + quad * 8];
    bf16x8 b0 = *(const bf16x8*)&sW[cch * AGG_LD + quad * 8];
    bf16x8 b1 = *(const bf16x8*)&sW[cch * AGG_LD + 32 + quad * 8];
    f32x4 d = {0.f, 0.f, 0.f, 0.f};
    d = __builtin_amdgcn_mfma_f32_16x16x32_bf16(a0, b0, d, 0, 0, 0);
    d = __builtin_amdgcn_mfma_f32_16x16x32_bf16(a1, b1, d, 0, 0, 0);
    // C layout: lane holds rows quad*4+reg of column cch
    float bias = b[cch];
    float v[4];
#pragma unroll
    for (int r = 0; r < 4; r++) {
        float z = d[r] + bias;
        v[r] = z > 0.0f ? z : 0.0f;
    }

    // Phase C: pool from registers (batch sorted -> tile usually one graph)
    int glo = batch[n0];
    int ghi = batch[n0 + 15];
    if (glo == ghi) {
        float s4 = (v[0] + v[1]) + (v[2] + v[3]);
        s4 += __shfl_xor(s4, 16, 64);
        s4 += __shfl_xor(s4, 32, 64);
        if (quad == 0) atomicAdd(&sums[glo * HIDDEN + cch], s4);
        if (t == 0) atomicAdd(&cntg[glo], 16.0f);
    } else {
#pragma unroll
        for (int r = 0; r < 4; r++) {
            int g = batch[n0 + quad * 4 + r];
            if ((unsigned)g < N_GRAPHS) atomicAdd(&sums[g * HIDDEN + cch], v[r]);
        }
        if (w == 0 && col == 0) {
#pragma unroll
            for (int r = 0; r < 4; r++) {
                int g = batch[n0 + quad * 4 + r];
                if ((unsigned)g < N_GRAPHS) atomicAdd(&cntg[g], 1.0f);
            }
        }
    }
}

// ---------------- head ----------------

__global__ void head_kernel(const float* __restrict__ sums, const float* __restrict__ cntg,
                            const float* __restrict__ Wc, const float* __restrict__ bc,
                            float* __restrict__ out) {
    int t = blockIdx.x * blockDim.x + threadIdx.x;
    if (t >= N_GRAPHS * OUT_CH) return;
    int g = t >> 1;
    int o = t & 1;
    float inv = 1.0f / fmaxf(cntg[g], 1.0f);
    float acc = bc[o];
#pragma unroll
    for (int k = 0; k < HIDDEN; k++) acc += sums[g * HIDDEN + k] * inv * Wc[k * OUT_CH + o];
    out[t] = acc;
}

// ---------------- launch ----------------

extern "C" void kernel_launch(void* const* d_in, const int* in_sizes, int n_in,
                              void* d_out, int out_size, void* d_ws, size_t ws_size,
                              hipStream_t stream) {
    const float* x  = (const float*)d_in[0];
    const int* ei   = (const int*)d_in[1];
    const int* bat  = (const int*)d_in[2];
    const float* W1 = (const float*)d_in[3];
    const float* b1 = (const float*)d_in[4];
    const float* W2 = (const float*)d_in[5];
    const float* b2 = (const float*)d_in[6];
    const float* Wc = (const float*)d_in[7];
    const float* bc = (const float*)d_in[8];
    float* out = (float*)d_out;

    const int* src = ei;
    const int* dst = ei + N_EDGES;

    char* ws = (char*)d_ws;
    size_t off = 0;
    auto carve = [&](size_t nbytes) {
        char* p = ws + off;
        off += (nbytes + 255) & ~(size_t)255;
        return p;
    };
    float* sums     = (float*)carve(N_GRAPHS * HIDDEN * sizeof(float));
    float* cntg     = (float*)carve(N_GRAPHS * sizeof(float));
    int*   bh       = (int*)carve((size_t)SLEN * sizeof(int));
    int*   bsum     = (int*)carve(NSB * sizeof(int));
    int*   boff     = (int*)carve((size_t)SLEN * sizeof(int));
    int2*  pairs    = (int2*)carve((size_t)N_EDGES * sizeof(int2));
    int*   csr      = (int*)carve((size_t)N_EDGES * sizeof(int));
    int*   rowptr   = (int*)carve(N_NODES * sizeof(int));
    int*   cnt_node = (int*)carve(N_NODES * sizeof(int));
    float* dinv     = (float*)carve(N_NODES * sizeof(float));
    __hip_bfloat16* bufA = (__hip_bfloat16*)carve((size_t)N_NODES * HIDDEN * sizeof(__hip_bfloat16));
    (void)ws_size;

    const int node16Blk = (N_NODES + 15) / 16;   // 3125 (50000 divisible by 16)

    bucket_hist_kernel<<<EB, 256, 0, stream>>>(dst, bh, sums, cntg);
    scan_part_kernel<<<NSB, 256, 0, stream>>>(bh, bsum);
    scan_apply_kernel<<<NSB, 256, 0, stream>>>(bh, bsum, boff);
    bucket_scatter_kernel<<<EB, 256, 0, stream>>>(src, dst, boff, pairs);
    bucket_csr_kernel<<<NB, 256, 0, stream>>>(pairs, boff, csr, rowptr, cnt_node, dinv);

    fused_l1_kernel<<<node16Blk, 256, 0, stream>>>(x, csr, rowptr, cnt_node, dinv, W1, b1, bufA);
    fused_l2_kernel<<<node16Blk, 256, 0, stream>>>(bufA, csr, rowptr, cnt_node, dinv, W2, b2,
                                                   bat, sums, cntg);
    head_kernel<<<1, 256, 0, stream>>>(sums, cntg, Wc, bc, out);
}

// Round 11
// 171.870 us; speedup vs baseline: 1.1168x; 1.0361x over previous
//
#include <hip/hip_runtime.h>
#include <hip/hip_bf16.h>

#define N_NODES 50000
#define N_EDGES 800000
#define N_GRAPHS 128
#define IN_CH 16
#define HIDDEN 64
#define OUT_CH 2

// ---- bucket-sort CSR build params ----
#define BSHIFT 7
#define BNODES 128
#define NB ((N_NODES + BNODES - 1) / BNODES)     // 391 buckets
#define ECHUNK 4096
#define EB ((N_EDGES + ECHUNK - 1) / ECHUNK)     // 196 edge blocks
#define SLEN (NB * EB)                           // 76636 scan entries
#define SCHUNK 1024
#define NSB ((SLEN + SCHUNK - 1) / SCHUNK)       // 75 (<= 256)
#define MAXK 12
#define WT1_LD 18                                // W1^T stride: 2-way banks (free)
#define AGG_LD 72                                // bf16 LDS stride for MFMA frags
#define W2T_ENT (HIDDEN * AGG_LD)                // 4608 ushorts = 9216 B prepped W2^T

typedef __attribute__((ext_vector_type(8))) short bf16x8;
typedef __attribute__((ext_vector_type(4))) float f32x4;

__device__ __forceinline__ float bf2f(unsigned short u) {
    return __uint_as_float(((unsigned)u) << 16);
}
__device__ __forceinline__ unsigned short f2bf(float f) {
    __hip_bfloat16 h = __float2bfloat16(f);
    return *reinterpret_cast<unsigned short*>(&h);
}

// ---------------- CSR build: LDS bucket sort (no global returning atomics) ----------------

// Block 0 zeroes sums|cntg; block 1 preps W2^T bf16 (padded layout) for fused_l2.
__global__ void bucket_hist_kernel(const int* __restrict__ dst, int* __restrict__ bh,
                                   float* __restrict__ sums, float* __restrict__ cntg,
                                   const float* __restrict__ W2, unsigned short* __restrict__ w2t) {
    __shared__ int lh[NB];
    int t = threadIdx.x;
    if (blockIdx.x == 0) {
        for (int i = t; i < N_GRAPHS * HIDDEN; i += 256) sums[i] = 0.0f;
        if (t < N_GRAPHS) cntg[t] = 0.0f;
    }
    if (blockIdx.x == 1) {
        for (int i = t; i < HIDDEN * HIDDEN; i += 256) {
            int k = i >> 6, c = i & 63;
            w2t[c * AGG_LD + k] = f2bf(W2[i]);
        }
    }
    for (int i = t; i < NB; i += 256) lh[i] = 0;
    __syncthreads();
    int base = blockIdx.x * ECHUNK;
    for (int i = t; i < ECHUNK; i += 256) {
        int e = base + i;
        if (e < N_EDGES) {
            int d = dst[e];
            if ((unsigned)d < N_NODES) atomicAdd(&lh[d >> BSHIFT], 1);
        }
    }
    __syncthreads();
    for (int i = t; i < NB; i += 256) bh[i * EB + blockIdx.x] = lh[i];
}

__global__ void scan_part_kernel(const int* __restrict__ a, int* __restrict__ bsum) {
    __shared__ int s[256];
    int t = threadIdx.x;
    int ebase = blockIdx.x * SCHUNK + t * 4;
    int v = 0;
    if (ebase + 3 < SLEN) {
        int4 c = *(const int4*)&a[ebase];
        v = c.x + c.y + c.z + c.w;
    } else {
        for (int k = 0; k < 4; k++) {
            int i = ebase + k;
            if (i < SLEN) v += a[i];
        }
    }
    s[t] = v;
    __syncthreads();
    for (int off = 128; off > 0; off >>= 1) {
        if (t < off) s[t] += s[t + off];
        __syncthreads();
    }
    if (t == 0) bsum[blockIdx.x] = s[0];
}

__global__ void scan_apply_kernel(const int* __restrict__ a, const int* __restrict__ bsum,
                                  int* __restrict__ boff) {
    __shared__ int sb[256];
    __shared__ int st[256];
    int t = threadIdx.x;
    sb[t] = (t < NSB) ? bsum[t] : 0;
    __syncthreads();
    for (int off = 1; off < 256; off <<= 1) {
        int u = (t >= off) ? sb[t - off] : 0;
        __syncthreads();
        sb[t] += u;
        __syncthreads();
    }
    int blockOff = (blockIdx.x > 0) ? sb[blockIdx.x - 1] : 0;

    int ebase = blockIdx.x * SCHUNK + t * 4;
    int c0 = 0, c1 = 0, c2 = 0, c3 = 0;
    bool full = (ebase + 3 < SLEN);
    if (full) {
        int4 c = *(const int4*)&a[ebase];
        c0 = c.x; c1 = c.y; c2 = c.z; c3 = c.w;
    } else {
        if (ebase < SLEN) c0 = a[ebase];
        if (ebase + 1 < SLEN) c1 = a[ebase + 1];
        if (ebase + 2 < SLEN) c2 = a[ebase + 2];
    }
    int tsum = c0 + c1 + c2 + c3;
    st[t] = tsum;
    __syncthreads();
    for (int off = 1; off < 256; off <<= 1) {
        int u = (t >= off) ? st[t - off] : 0;
        __syncthreads();
        st[t] += u;
        __syncthreads();
    }
    int p = blockOff + st[t] - tsum;
    if (full) {
        int4 o;
        o.x = p; o.y = p + c0; o.z = p + c0 + c1; o.w = p + c0 + c1 + c2;
        *(int4*)&boff[ebase] = o;
    } else {
        if (ebase < SLEN) boff[ebase] = p;
        if (ebase + 1 < SLEN) boff[ebase + 1] = p + c0;
        if (ebase + 2 < SLEN) boff[ebase + 2] = p + c0 + c1;
        if (ebase + 3 < SLEN) boff[ebase + 3] = p + c0 + c1 + c2;
    }
}

// S3: scatter packed (src<<7 | node-low-bits) into bucket regions.
__global__ void bucket_scatter_kernel(const int* __restrict__ src, const int* __restrict__ dst,
                                      const int* __restrict__ boff, int* __restrict__ pairs) {
    __shared__ int lcnt[NB];
    __shared__ int goff[NB];
    int t = threadIdx.x;
    for (int i = t; i < NB; i += 256) {
        lcnt[i] = 0;
        goff[i] = boff[i * EB + blockIdx.x];
    }
    __syncthreads();
    int base = blockIdx.x * ECHUNK;
    for (int i = t; i < ECHUNK; i += 256) {
        int e = base + i;
        if (e < N_EDGES) {
            int d = dst[e];
            if ((unsigned)d < N_NODES) {
                int b = d >> BSHIFT;
                int r = atomicAdd(&lcnt[b], 1);
                pairs[goff[b] + r] = (src[e] << BSHIFT) | (d & (BNODES - 1));
            }
        }
    }
}

__global__ void bucket_csr_kernel(const int* __restrict__ pairs, const int* __restrict__ boff,
                                  int* __restrict__ csr, int* __restrict__ rowptr,
                                  int* __restrict__ cnt_node, float* __restrict__ dinv) {
    __shared__ int lcnt[BNODES];
    __shared__ int ls[BNODES];
    __shared__ int lrow[BNODES];
    int b = blockIdx.x;
    int t = threadIdx.x;
    if (t < BNODES) lcnt[t] = 0;
    __syncthreads();
    int bstart = boff[b * EB];
    int bend = (b + 1 < NB) ? boff[(b + 1) * EB] : N_EDGES;
    int K = bend - bstart;
    int myp[MAXK], myr[MAXK];
#pragma unroll
    for (int k = 0; k < MAXK; k++) {
        int i = k * 256 + t;
        if (i < K) {
            int p = pairs[bstart + i];
            myp[k] = p;
            myr[k] = atomicAdd(&lcnt[p & (BNODES - 1)], 1);
        }
    }
    __syncthreads();
    if (t < BNODES) ls[t] = lcnt[t];
    __syncthreads();
    for (int off = 1; off < BNODES; off <<= 1) {
        int u = (t >= off && t < BNODES) ? ls[t - off] : 0;
        __syncthreads();
        if (t < BNODES) ls[t] += u;
        __syncthreads();
    }
    if (t < BNODES) {
        int ex = ls[t] - lcnt[t];
        lrow[t] = ex;
        int n = b * BNODES + t;
        if (n < N_NODES) {
            rowptr[n] = bstart + ex;
            cnt_node[n] = lcnt[t];
            dinv[n] = rsqrtf((float)(lcnt[t] + 1));  // +1 self-loop
        }
    }
    __syncthreads();
#pragma unroll
    for (int k = 0; k < MAXK; k++) {
        int i = k * 256 + t;
        if (i < K) csr[bstart + lrow[myp[k] & (BNODES - 1)] + myr[k]] = myp[k] >> BSHIFT;
    }
}

// ---------------- fused layer 1: aggregate(x) -> LDS -> linear+relu -> h1' (bf16, pre-scaled) ----------------

__global__ void fused_l1_kernel(const float* __restrict__ x, const int* __restrict__ csr_src,
                                const int* __restrict__ rowptr, const int* __restrict__ cnt,
                                const float* __restrict__ dinv, const float* __restrict__ W,
                                const float* __restrict__ b, __hip_bfloat16* __restrict__ h) {
    __shared__ float sWT[HIDDEN * WT1_LD];   // 4.6 KB
    __shared__ float sx[16 * IN_CH];         // 1 KB
    int t = threadIdx.x;
    for (int i = t; i < IN_CH * HIDDEN; i += 256) {
        int k = i >> 6, c = i & 63;
        sWT[c * WT1_LD + k] = W[i];
    }

    int n0 = blockIdx.x * 16;
    int w = t >> 6;
    int lane = t & 63;
    int e16 = lane >> 2;          // edge slot 0..15
    int cc = (lane & 3) * 4;      // channel quad

    int lens[4], starts[4];
#pragma unroll
    for (int q = 0; q < 4; q++) {
        int n = n0 + w * 4 + q;
        lens[q] = cnt[n];
        starts[q] = rowptr[n];
    }

    for (int q = 0; q < 4; q++) {
        int row = w * 4 + q;
        int n = n0 + row;
        int len = lens[q];
        int start = starts[q];
        float4 acc = make_float4(0.f, 0.f, 0.f, 0.f);
        for (int i = e16; i < len; i += 16) {
            int s = csr_src[start + i];
            float dv = dinv[s];
            float4 xv = *(const float4*)&x[s * IN_CH + cc];
            acc.x += dv * xv.x; acc.y += dv * xv.y;
            acc.z += dv * xv.z; acc.w += dv * xv.w;
        }
#pragma unroll
        for (int m = 4; m <= 32; m <<= 1) {
            acc.x += __shfl_xor(acc.x, m, 64);
            acc.y += __shfl_xor(acc.y, m, 64);
            acc.z += __shfl_xor(acc.z, m, 64);
            acc.w += __shfl_xor(acc.w, m, 64);
        }
        if (lane < 4) {
            float dn = dinv[n];
            float4 xs = *(const float4*)&x[n * IN_CH + cc];
            float4 v;
            v.x = dn * acc.x + dn * dn * xs.x;
            v.y = dn * acc.y + dn * dn * xs.y;
            v.z = dn * acc.z + dn * dn * xs.z;
            v.w = dn * acc.w + dn * dn * xs.w;
            *(float4*)&sx[row * IN_CH + cc] = v;
        }
    }
    __syncthreads();

    int r = w;
    int c = t & 63;
    float bias = b[c];
#pragma unroll
    for (int nb = 0; nb < 4; nb++) {
        int row = nb * 4 + r;
        int n = n0 + row;
        if (n >= N_NODES) continue;
        float acch = bias;
#pragma unroll
        for (int k4 = 0; k4 < IN_CH; k4 += 4) {
            float4 a = *(const float4*)&sx[row * IN_CH + k4];
            float2 w0 = *(const float2*)&sWT[c * WT1_LD + k4];
            float2 w1 = *(const float2*)&sWT[c * WT1_LD + k4 + 2];
            acch += a.x * w0.x + a.y * w0.y + a.z * w1.x + a.w * w1.y;
        }
        float v = acch > 0.0f ? acch : 0.0f;
        h[n * HIDDEN + c] = __float2bfloat16(dinv[n] * v);   // pre-scaled h1'
    }
}

// ---------------- fused layer 2: aggregate(h1') -> bf16 LDS -> MFMA gemm2 -> pool ----------------

// Phase A: wave-uniform iteration count, 4 clamped+masked slots per iter
// (constant 4 gathers in flight, no serial remainder, no divergent bounds).
// Phase B: two v_mfma_f32_16x16x32_bf16. Phase C: pool from C-layout registers.
__global__ void fused_l2_kernel(const __hip_bfloat16* __restrict__ h, const int* __restrict__ csr_src,
                                const int* __restrict__ rowptr, const int* __restrict__ cnt,
                                const float* __restrict__ dinv, const unsigned short* __restrict__ w2t,
                                const float* __restrict__ b, const int* __restrict__ batch,
                                float* __restrict__ sums, float* __restrict__ cntg) {
    __shared__ unsigned short sW[W2T_ENT];           // 9.2 KB (prepped, flat copy)
    __shared__ unsigned short sagg[16 * AGG_LD];     // 2.3 KB
    int t = threadIdx.x;
    {   // flat uint4 copy of prepped W2^T (conflict-free b128)
        const uint4* wp = (const uint4*)w2t;
        uint4* sWv = (uint4*)sW;
#pragma unroll
        for (int i = 0; i < 3; i++) {
            int idx = i * 256 + t;
            if (idx < W2T_ENT / 8) sWv[idx] = wp[idx];
        }
    }

    int n0 = blockIdx.x * 16;
    int w = t >> 6;
    int lane = t & 63;
    int e4 = lane >> 4;          // edge slot 0..3
    int cc = (lane & 15) * 4;    // channel quad
    const unsigned short* hu = (const unsigned short*)h;

    int lens[4], starts[4];
#pragma unroll
    for (int q = 0; q < 4; q++) {
        int n = n0 + w * 4 + q;
        lens[q] = cnt[n];
        starts[q] = rowptr[n];
    }

    for (int q = 0; q < 4; q++) {
        int row = w * 4 + q;
        int n = n0 + row;
        int len = lens[q];
        int start = starts[q];
        float4 acc = make_float4(0.f, 0.f, 0.f, 0.f);
        int last = len - 1;
        int iters = (len + 15) >> 4;             // wave-uniform
        for (int m = 0; m < iters; m++) {
            int base = m * 16 + e4;
#pragma unroll
            for (int k = 0; k < 4; k++) {
                int j = base + 4 * k;
                int jj = j <= last ? j : last;    // clamped (safe) index
                float msk = j <= last ? 1.0f : 0.0f;
                int s = csr_src[start + jj];
                ushort4 a = *(const ushort4*)&hu[s * HIDDEN + cc];
                acc.x += msk * bf2f(a.x);
                acc.y += msk * bf2f(a.y);
                acc.z += msk * bf2f(a.z);
                acc.w += msk * bf2f(a.w);
            }
        }
        acc.x += __shfl_xor(acc.x, 16, 64);
        acc.y += __shfl_xor(acc.y, 16, 64);
        acc.z += __shfl_xor(acc.z, 16, 64);
        acc.w += __shfl_xor(acc.w, 16, 64);
        acc.x += __shfl_xor(acc.x, 32, 64);
        acc.y += __shfl_xor(acc.y, 32, 64);
        acc.z += __shfl_xor(acc.z, 32, 64);
        acc.w += __shfl_xor(acc.w, 32, 64);
        if (lane < 16) {
            ushort4 sv = *(const ushort4*)&hu[n * HIDDEN + cc];
            float dn = dinv[n];
            ushort4 o;
            o.x = f2bf(dn * (acc.x + bf2f(sv.x)));
            o.y = f2bf(dn * (acc.y + bf2f(sv.y)));
            o.z = f2bf(dn * (acc.z + bf2f(sv.z)));
            o.w = f2bf(dn * (acc.w + bf2f(sv.w)));
            *(ushort4*)&sagg[row * AGG_LD + cc] = o;
        }
    }
    __syncthreads();

    // Phase B: MFMA. Wave w computes all 16 nodes x channels [16w, 16w+16).
    int quad = lane >> 4;
    int col = lane & 15;
    int cch = w * 16 + col;
    bf16x8 a0 = *(const bf16x8*)&sagg[col * AGG_LD + quad * 8];
    bf16x8 a1 = *(const bf16x8*)&sagg[col * AGG_LD + 32 + quad * 8];
    bf16x8 b0 = *(const bf16x8*)&sW[cch * AGG_LD + quad * 8];
    bf16x8 b1 = *(const bf16x8*)&sW[cch * AGG_LD + 32 + quad * 8];
    f32x4 d = {0.f, 0.f, 0.f, 0.f};
    d = __builtin_amdgcn_mfma_f32_16x16x32_bf16(a0, b0, d, 0, 0, 0);
    d = __builtin_amdgcn_mfma_f32_16x16x32_bf16(a1, b1, d, 0, 0, 0);
    float bias = b[cch];
    float v[4];
#pragma unroll
    for (int r = 0; r < 4; r++) {
        float z = d[r] + bias;
        v[r] = z > 0.0f ? z : 0.0f;
    }

    // Phase C: pool from registers (batch sorted -> tile usually one graph)
    int glo = batch[n0];
    int ghi = batch[n0 + 15];
    if (glo == ghi) {
        float s4 = (v[0] + v[1]) + (v[2] + v[3]);
        s4 += __shfl_xor(s4, 16, 64);
        s4 += __shfl_xor(s4, 32, 64);
        if (quad == 0) atomicAdd(&sums[glo * HIDDEN + cch], s4);
        if (t == 0) atomicAdd(&cntg[glo], 16.0f);
    } else {
#pragma unroll
        for (int r = 0; r < 4; r++) {
            int g = batch[n0 + quad * 4 + r];
            if ((unsigned)g < N_GRAPHS) atomicAdd(&sums[g * HIDDEN + cch], v[r]);
        }
        if (w == 0 && col == 0) {
#pragma unroll
            for (int r = 0; r < 4; r++) {
                int g = batch[n0 + quad * 4 + r];
                if ((unsigned)g < N_GRAPHS) atomicAdd(&cntg[g], 1.0f);
            }
        }
    }
}

// ---------------- head ----------------

__global__ void head_kernel(const float* __restrict__ sums, const float* __restrict__ cntg,
                            const float* __restrict__ Wc, const float* __restrict__ bc,
                            float* __restrict__ out) {
    int t = blockIdx.x * blockDim.x + threadIdx.x;
    if (t >= N_GRAPHS * OUT_CH) return;
    int g = t >> 1;
    int o = t & 1;
    float inv = 1.0f / fmaxf(cntg[g], 1.0f);
    float acc = bc[o];
#pragma unroll
    for (int k = 0; k < HIDDEN; k++) acc += sums[g * HIDDEN + k] * inv * Wc[k * OUT_CH + o];
    out[t] = acc;
}

// ---------------- launch ----------------

extern "C" void kernel_launch(void* const* d_in, const int* in_sizes, int n_in,
                              void* d_out, int out_size, void* d_ws, size_t ws_size,
                              hipStream_t stream) {
    const float* x  = (const float*)d_in[0];
    const int* ei   = (const int*)d_in[1];
    const int* bat  = (const int*)d_in[2];
    const float* W1 = (const float*)d_in[3];
    const float* b1 = (const float*)d_in[4];
    const float* W2 = (const float*)d_in[5];
    const float* b2 = (const float*)d_in[6];
    const float* Wc = (const float*)d_in[7];
    const float* bc = (const float*)d_in[8];
    float* out = (float*)d_out;

    const int* src = ei;
    const int* dst = ei + N_EDGES;

    char* ws = (char*)d_ws;
    size_t off = 0;
    auto carve = [&](size_t nbytes) {
        char* p = ws + off;
        off += (nbytes + 255) & ~(size_t)255;
        return p;
    };
    float* sums     = (float*)carve(N_GRAPHS * HIDDEN * sizeof(float));
    float* cntg     = (float*)carve(N_GRAPHS * sizeof(float));
    unsigned short* w2t = (unsigned short*)carve(W2T_ENT * sizeof(unsigned short));
    int*   bh       = (int*)carve((size_t)SLEN * sizeof(int));
    int*   bsum     = (int*)carve(NSB * sizeof(int));
    int*   boff     = (int*)carve((size_t)SLEN * sizeof(int));
    int*   pairs    = (int*)carve((size_t)N_EDGES * sizeof(int));
    int*   csr      = (int*)carve((size_t)N_EDGES * sizeof(int));
    int*   rowptr   = (int*)carve(N_NODES * sizeof(int));
    int*   cnt_node = (int*)carve(N_NODES * sizeof(int));
    float* dinv     = (float*)carve(N_NODES * sizeof(float));
    __hip_bfloat16* bufA = (__hip_bfloat16*)carve((size_t)N_NODES * HIDDEN * sizeof(__hip_bfloat16));
    (void)ws_size;

    const int node16Blk = (N_NODES + 15) / 16;   // 3125

    bucket_hist_kernel<<<EB, 256, 0, stream>>>(dst, bh, sums, cntg, W2, w2t);
    scan_part_kernel<<<NSB, 256, 0, stream>>>(bh, bsum);
    scan_apply_kernel<<<NSB, 256, 0, stream>>>(bh, bsum, boff);
    bucket_scatter_kernel<<<EB, 256, 0, stream>>>(src, dst, boff, pairs);
    bucket_csr_kernel<<<NB, 256, 0, stream>>>(pairs, boff, csr, rowptr, cnt_node, dinv);

    fused_l1_kernel<<<node16Blk, 256, 0, stream>>>(x, csr, rowptr, cnt_node, dinv, W1, b1, bufA);
    fused_l2_kernel<<<node16Blk, 256, 0, stream>>>(bufA, csr, rowptr, cnt_node, dinv, w2t, b2,
                                                   bat, sums, cntg);
    head_kernel<<<1, 256, 0, stream>>>(sums, cntg, Wc, bc, out);
}

// Round 12
// 167.606 us; speedup vs baseline: 1.1452x; 1.0254x over previous
//
#include <hip/hip_runtime.h>
#include <hip/hip_bf16.h>

#define N_NODES 50000
#define N_EDGES 800000
#define N_GRAPHS 128
#define IN_CH 16
#define HIDDEN 64
#define OUT_CH 2

// ---- bucket CSR params ----
#define BSHIFT 7
#define BNODES 128
#define NB ((N_NODES + BNODES - 1) / BNODES)     // 391 buckets
#define BCAP 3072                                // fixed bucket capacity (mean 2046, sd ~45)
#define ECHUNK 4096
#define EB ((N_EDGES + ECHUNK - 1) / ECHUNK)     // 196 edge blocks
#define MAXK 12                                  // BCAP/256
#define WT1_LD 18                                // W1^T stride: 2-way banks (free)
#define AGG_LD 72                                // bf16 LDS stride for MFMA frags
#define W2T_ENT (HIDDEN * AGG_LD)                // 4608 ushorts prepped W2^T

typedef __attribute__((ext_vector_type(8))) short bf16x8;
typedef __attribute__((ext_vector_type(4))) float f32x4;

__device__ __forceinline__ float bf2f(unsigned short u) {
    return __uint_as_float(((unsigned)u) << 16);
}
__device__ __forceinline__ unsigned short f2bf(float f) {
    __hip_bfloat16 h = __float2bfloat16(f);
    return *reinterpret_cast<unsigned short*>(&h);
}

// ---------------- init: zero sums|cntg|bcnt, prep W2^T bf16 ----------------

__global__ void init_kernel(int* __restrict__ zbase, int zwords,
                            const float* __restrict__ W2, unsigned short* __restrict__ w2t) {
    int gid = blockIdx.x * 256 + threadIdx.x;
    int gsz = gridDim.x * 256;
    for (int i = gid; i < zwords; i += gsz) zbase[i] = 0;
    for (int i = gid; i < HIDDEN * HIDDEN; i += gsz) {
        int k = i >> 6, c = i & 63;
        w2t[c * AGG_LD + k] = f2bf(W2[i]);
    }
}

// ---------------- CSR build: direct bucket scatter (fixed-capacity regions) ----------------

// Pass 1: LDS histogram of this block's 4096 edges per bucket.
// Reserve: one returning global atomic per non-empty (block,bucket) (~391/block).
// Pass 2: scatter packed (src<<7|node-low) into bucket region.
__global__ void bucket_scatter_kernel(const int* __restrict__ src, const int* __restrict__ dst,
                                      int* __restrict__ bcnt, int* __restrict__ pairs) {
    __shared__ int lcnt[NB];
    __shared__ int goff[NB];
    __shared__ int lcur[NB];
    int t = threadIdx.x;
    for (int i = t; i < NB; i += 256) lcnt[i] = 0;
    __syncthreads();
    int base = blockIdx.x * ECHUNK;
    for (int i = t; i < ECHUNK; i += 256) {
        int e = base + i;
        if (e < N_EDGES) {
            int d = dst[e];
            if ((unsigned)d < N_NODES) atomicAdd(&lcnt[d >> BSHIFT], 1);
        }
    }
    __syncthreads();
    for (int i = t; i < NB; i += 256) {
        int c = lcnt[i];
        goff[i] = (c > 0) ? atomicAdd(&bcnt[i], c) : 0;
        lcur[i] = 0;
    }
    __syncthreads();
    for (int i = t; i < ECHUNK; i += 256) {
        int e = base + i;
        if (e < N_EDGES) {
            int d = dst[e];
            if ((unsigned)d < N_NODES) {
                int b = d >> BSHIFT;
                int r = goff[b] + atomicAdd(&lcur[b], 1);
                if (r < BCAP) pairs[b * BCAP + r] = (src[e] << BSHIFT) | (d & (BNODES - 1));
            }
        }
    }
}

// One block per bucket: per-node ranks via LDS atomics, 128-wide scan -> rowptr/cnt/dinv,
// write final csr. Also preps x' = dinv*x (fp32) for this bucket's nodes.
__global__ void bucket_csr_kernel(const int* __restrict__ pairs, const int* __restrict__ bcnt,
                                  int* __restrict__ csr, int* __restrict__ rowptr,
                                  int* __restrict__ cnt_node, float* __restrict__ dinv,
                                  const float* __restrict__ x, float* __restrict__ xs) {
    __shared__ int lcnt[BNODES];
    __shared__ int ls[BNODES];
    __shared__ int lrow[BNODES];
    __shared__ float sdv[BNODES];
    int b = blockIdx.x;
    int t = threadIdx.x;
    if (t < BNODES) lcnt[t] = 0;
    __syncthreads();
    int bstart = b * BCAP;
    int K = bcnt[b];
    if (K > BCAP) K = BCAP;
    int myp[MAXK], myr[MAXK];
#pragma unroll
    for (int k = 0; k < MAXK; k++) {
        int i = k * 256 + t;
        if (i < K) {
            int p = pairs[bstart + i];
            myp[k] = p;
            myr[k] = atomicAdd(&lcnt[p & (BNODES - 1)], 1);
        }
    }
    __syncthreads();
    if (t < BNODES) ls[t] = lcnt[t];
    __syncthreads();
    for (int off = 1; off < BNODES; off <<= 1) {
        int u = (t >= off && t < BNODES) ? ls[t - off] : 0;
        __syncthreads();
        if (t < BNODES) ls[t] += u;
        __syncthreads();
    }
    if (t < BNODES) {
        int ex = ls[t] - lcnt[t];
        lrow[t] = ex;
        float dv = rsqrtf((float)(lcnt[t] + 1));  // +1 self-loop
        sdv[t] = dv;
        int n = b * BNODES + t;
        if (n < N_NODES) {
            rowptr[n] = bstart + ex;
            cnt_node[n] = lcnt[t];
            dinv[n] = dv;
        }
    }
    __syncthreads();
#pragma unroll
    for (int k = 0; k < MAXK; k++) {
        int i = k * 256 + t;
        if (i < K) csr[bstart + lrow[myp[k] & (BNODES - 1)] + myr[k]] = myp[k] >> BSHIFT;
    }
    // prep x' = dinv * x for this bucket's 128 nodes (2048 floats)
    for (int i = t; i < BNODES * IN_CH; i += 256) {
        int nl = i >> 4;
        int n = b * BNODES + nl;
        if (n < N_NODES) xs[n * IN_CH + (i & 15)] = sdv[nl] * x[n * IN_CH + (i & 15)];
    }
}

// ---------------- fused layer 1: aggregate(x') -> LDS -> linear+relu -> h1' (bf16, pre-scaled) ----------------

// Phase A: 4 lanes/edge, float4 per lane; wave-uniform iters, 2 clamped+masked slots
// (32 edges in flight per row). No per-edge dinv (x' pre-scaled).
__global__ void fused_l1_kernel(const float* __restrict__ xs, const int* __restrict__ csr_src,
                                const int* __restrict__ rowptr, const int* __restrict__ cnt,
                                const float* __restrict__ dinv, const float* __restrict__ W,
                                const float* __restrict__ b, __hip_bfloat16* __restrict__ h) {
    __shared__ float sWT[HIDDEN * WT1_LD];   // 4.6 KB
    __shared__ float sx[16 * IN_CH];         // 1 KB
    int t = threadIdx.x;
    for (int i = t; i < IN_CH * HIDDEN; i += 256) {
        int k = i >> 6, c = i & 63;
        sWT[c * WT1_LD + k] = W[i];
    }

    int n0 = blockIdx.x * 16;
    int w = t >> 6;
    int lane = t & 63;
    int e16 = lane >> 2;          // edge slot 0..15
    int cc = (lane & 3) * 4;      // channel quad

    int lens[4], starts[4];
#pragma unroll
    for (int q = 0; q < 4; q++) {
        int n = n0 + w * 4 + q;
        lens[q] = cnt[n];
        starts[q] = rowptr[n];
    }

    for (int q = 0; q < 4; q++) {
        int row = w * 4 + q;
        int n = n0 + row;
        int len = lens[q];
        int start = starts[q];
        int last = len - 1;
        int iters = (len + 31) >> 5;   // wave-uniform, 32 edges per iter
        float4 acc = make_float4(0.f, 0.f, 0.f, 0.f);
        for (int m = 0; m < iters; m++) {
            int base = m * 32 + e16;
#pragma unroll
            for (int k = 0; k < 2; k++) {
                int j = base + 16 * k;
                int jj = j <= last ? j : last;
                float msk = j <= last ? 1.0f : 0.0f;
                int s = csr_src[start + jj];
                float4 xv = *(const float4*)&xs[s * IN_CH + cc];
                acc.x += msk * xv.x; acc.y += msk * xv.y;
                acc.z += msk * xv.z; acc.w += msk * xv.w;
            }
        }
#pragma unroll
        for (int m = 4; m <= 32; m <<= 1) {
            acc.x += __shfl_xor(acc.x, m, 64);
            acc.y += __shfl_xor(acc.y, m, 64);
            acc.z += __shfl_xor(acc.z, m, 64);
            acc.w += __shfl_xor(acc.w, m, 64);
        }
        if (lane < 4) {
            float dn = dinv[n];
            float4 xsv = *(const float4*)&xs[n * IN_CH + cc];
            float4 v;
            v.x = dn * (acc.x + xsv.x);
            v.y = dn * (acc.y + xsv.y);
            v.z = dn * (acc.z + xsv.z);
            v.w = dn * (acc.w + xsv.w);
            *(float4*)&sx[row * IN_CH + cc] = v;
        }
    }
    __syncthreads();

    int r = w;
    int c = t & 63;
    float bias = b[c];
#pragma unroll
    for (int nb = 0; nb < 4; nb++) {
        int row = nb * 4 + r;
        int n = n0 + row;
        if (n >= N_NODES) continue;
        float acch = bias;
#pragma unroll
        for (int k4 = 0; k4 < IN_CH; k4 += 4) {
            float4 a = *(const float4*)&sx[row * IN_CH + k4];
            float2 w0 = *(const float2*)&sWT[c * WT1_LD + k4];
            float2 w1 = *(const float2*)&sWT[c * WT1_LD + k4 + 2];
            acch += a.x * w0.x + a.y * w0.y + a.z * w1.x + a.w * w1.y;
        }
        float v = acch > 0.0f ? acch : 0.0f;
        h[n * HIDDEN + c] = __float2bfloat16(dinv[n] * v);   // pre-scaled h1'
    }
}

// ---------------- fused layer 2: aggregate(h1') -> bf16 LDS -> MFMA gemm2 -> pool ----------------

// Phase A: 8 lanes/edge, ushort8 (16B dwordx4) per lane; wave-uniform iters,
// 4 clamped+masked slots = 32 edges in flight per row.
__global__ void fused_l2_kernel(const __hip_bfloat16* __restrict__ h, const int* __restrict__ csr_src,
                                const int* __restrict__ rowptr, const int* __restrict__ cnt,
                                const float* __restrict__ dinv, const unsigned short* __restrict__ w2t,
                                const float* __restrict__ b, const int* __restrict__ batch,
                                float* __restrict__ sums, float* __restrict__ cntg) {
    __shared__ unsigned short sW[W2T_ENT];           // 9.2 KB (prepped, flat copy)
    __shared__ unsigned short sagg[16 * AGG_LD];     // 2.3 KB
    int t = threadIdx.x;
    {   // flat uint4 copy of prepped W2^T (conflict-free b128)
        const uint4* wp = (const uint4*)w2t;
        uint4* sWv = (uint4*)sW;
#pragma unroll
        for (int i = 0; i < 3; i++) {
            int idx = i * 256 + t;
            if (idx < W2T_ENT / 8) sWv[idx] = wp[idx];
        }
    }

    int n0 = blockIdx.x * 16;
    int w = t >> 6;
    int lane = t & 63;
    int e8 = lane >> 3;          // edge slot 0..7
    int cc8 = (lane & 7) * 8;    // channel octet
    const unsigned short* hu = (const unsigned short*)h;

    int lens[4], starts[4];
#pragma unroll
    for (int q = 0; q < 4; q++) {
        int n = n0 + w * 4 + q;
        lens[q] = cnt[n];
        starts[q] = rowptr[n];
    }

    for (int q = 0; q < 4; q++) {
        int row = w * 4 + q;
        int n = n0 + row;
        int len = lens[q];
        int start = starts[q];
        int last = len - 1;
        int iters = (len + 31) >> 5;   // 32 edges per iter
        float4 alo = make_float4(0.f, 0.f, 0.f, 0.f);
        float4 ahi = make_float4(0.f, 0.f, 0.f, 0.f);
        for (int m = 0; m < iters; m++) {
            int base = m * 32 + e8;
#pragma unroll
            for (int k = 0; k < 4; k++) {
                int j = base + 8 * k;
                int jj = j <= last ? j : last;
                float msk = j <= last ? 1.0f : 0.0f;
                int s = csr_src[start + jj];
                uint4 raw = *(const uint4*)&hu[s * HIDDEN + cc8];
                alo.x += msk * __uint_as_float(raw.x << 16);
                alo.y += msk * __uint_as_float(raw.x & 0xffff0000u);
                alo.z += msk * __uint_as_float(raw.y << 16);
                alo.w += msk * __uint_as_float(raw.y & 0xffff0000u);
                ahi.x += msk * __uint_as_float(raw.z << 16);
                ahi.y += msk * __uint_as_float(raw.z & 0xffff0000u);
                ahi.z += msk * __uint_as_float(raw.w << 16);
                ahi.w += msk * __uint_as_float(raw.w & 0xffff0000u);
            }
        }
#pragma unroll
        for (int m = 8; m <= 32; m <<= 1) {
            alo.x += __shfl_xor(alo.x, m, 64);
            alo.y += __shfl_xor(alo.y, m, 64);
            alo.z += __shfl_xor(alo.z, m, 64);
            alo.w += __shfl_xor(alo.w, m, 64);
            ahi.x += __shfl_xor(ahi.x, m, 64);
            ahi.y += __shfl_xor(ahi.y, m, 64);
            ahi.z += __shfl_xor(ahi.z, m, 64);
            ahi.w += __shfl_xor(ahi.w, m, 64);
        }
        if (lane < 8) {
            uint4 sv = *(const uint4*)&hu[n * HIDDEN + cc8];
            float dn = dinv[n];
            ushort4 o0, o1;
            o0.x = f2bf(dn * (alo.x + __uint_as_float(sv.x << 16)));
            o0.y = f2bf(dn * (alo.y + __uint_as_float(sv.x & 0xffff0000u)));
            o0.z = f2bf(dn * (alo.z + __uint_as_float(sv.y << 16)));
            o0.w = f2bf(dn * (alo.w + __uint_as_float(sv.y & 0xffff0000u)));
            o1.x = f2bf(dn * (ahi.x + __uint_as_float(sv.z << 16)));
            o1.y = f2bf(dn * (ahi.y + __uint_as_float(sv.z & 0xffff0000u)));
            o1.z = f2bf(dn * (ahi.z + __uint_as_float(sv.w << 16)));
            o1.w = f2bf(dn * (ahi.w + __uint_as_float(sv.w & 0xffff0000u)));
            *(ushort4*)&sagg[row * AGG_LD + cc8] = o0;
            *(ushort4*)&sagg[row * AGG_LD + cc8 + 4] = o1;
        }
    }
    __syncthreads();

    // Phase B: MFMA. Wave w computes all 16 nodes x channels [16w, 16w+16).
    int quad = lane >> 4;
    int col = lane & 15;
    int cch = w * 16 + col;
    bf16x8 a0 = *(const bf16x8*)&sagg[col * AGG_LD + quad * 8];
    bf16x8 a1 = *(const bf16x8*)&sagg[col * AGG_LD + 32 + quad * 8];
    bf16x8 b0 = *(const bf16x8*)&sW[cch * AGG_LD + quad * 8];
    bf16x8 b1 = *(const bf16x8*)&sW[cch * AGG_LD + 32 + quad * 8];
    f32x4 d = {0.f, 0.f, 0.f, 0.f};
    d = __builtin_amdgcn_mfma_f32_16x16x32_bf16(a0, b0, d, 0, 0, 0);
    d = __builtin_amdgcn_mfma_f32_16x16x32_bf16(a1, b1, d, 0, 0, 0);
    float bias = b[cch];
    float v[4];
#pragma unroll
    for (int r = 0; r < 4; r++) {
        float z = d[r] + bias;
        v[r] = z > 0.0f ? z : 0.0f;
    }

    // Phase C: pool from registers (batch sorted -> tile usually one graph)
    int glo = batch[n0];
    int ghi = batch[n0 + 15];
    if (glo == ghi) {
        float s4 = (v[0] + v[1]) + (v[2] + v[3]);
        s4 += __shfl_xor(s4, 16, 64);
        s4 += __shfl_xor(s4, 32, 64);
        if (quad == 0) atomicAdd(&sums[glo * HIDDEN + cch], s4);
        if (t == 0) atomicAdd(&cntg[glo], 16.0f);
    } else {
#pragma unroll
        for (int r = 0; r < 4; r++) {
            int g = batch[n0 + quad * 4 + r];
            if ((unsigned)g < N_GRAPHS) atomicAdd(&sums[g * HIDDEN + cch], v[r]);
        }
        if (w == 0 && col == 0) {
#pragma unroll
            for (int r = 0; r < 4; r++) {
                int g = batch[n0 + quad * 4 + r];
                if ((unsigned)g < N_GRAPHS) atomicAdd(&cntg[g], 1.0f);
            }
        }
    }
}

// ---------------- head ----------------

__global__ void head_kernel(const float* __restrict__ sums, const float* __restrict__ cntg,
                            const float* __restrict__ Wc, const float* __restrict__ bc,
                            float* __restrict__ out) {
    int t = blockIdx.x * blockDim.x + threadIdx.x;
    if (t >= N_GRAPHS * OUT_CH) return;
    int g = t >> 1;
    int o = t & 1;
    float inv = 1.0f / fmaxf(cntg[g], 1.0f);
    float acc = bc[o];
#pragma unroll
    for (int k = 0; k < HIDDEN; k++) acc += sums[g * HIDDEN + k] * inv * Wc[k * OUT_CH + o];
    out[t] = acc;
}

// ---------------- launch ----------------

extern "C" void kernel_launch(void* const* d_in, const int* in_sizes, int n_in,
                              void* d_out, int out_size, void* d_ws, size_t ws_size,
                              hipStream_t stream) {
    const float* x  = (const float*)d_in[0];
    const int* ei   = (const int*)d_in[1];
    const int* bat  = (const int*)d_in[2];
    const float* W1 = (const float*)d_in[3];
    const float* b1 = (const float*)d_in[4];
    const float* W2 = (const float*)d_in[5];
    const float* b2 = (const float*)d_in[6];
    const float* Wc = (const float*)d_in[7];
    const float* bc = (const float*)d_in[8];
    float* out = (float*)d_out;

    const int* src = ei;
    const int* dst = ei + N_EDGES;

    char* ws = (char*)d_ws;
    size_t off = 0;
    auto carve = [&](size_t nbytes) {
        char* p = ws + off;
        off += (nbytes + 255) & ~(size_t)255;
        return p;
    };
    // contiguous zero region: sums | cntg | bcnt
    float* sums     = (float*)carve(N_GRAPHS * HIDDEN * sizeof(float));
    float* cntg     = (float*)carve(N_GRAPHS * sizeof(float));
    int*   bcnt     = (int*)carve(NB * sizeof(int));
    size_t zeroBytes = off;
    unsigned short* w2t = (unsigned short*)carve(W2T_ENT * sizeof(unsigned short));
    int*   pairs    = (int*)carve((size_t)NB * BCAP * sizeof(int));
    int*   csr      = (int*)carve((size_t)NB * BCAP * sizeof(int));
    int*   rowptr   = (int*)carve(N_NODES * sizeof(int));
    int*   cnt_node = (int*)carve(N_NODES * sizeof(int));
    float* dinv     = (float*)carve(N_NODES * sizeof(float));
    float* xs       = (float*)carve((size_t)N_NODES * IN_CH * sizeof(float));
    __hip_bfloat16* bufA = (__hip_bfloat16*)carve((size_t)N_NODES * HIDDEN * sizeof(__hip_bfloat16));
    (void)ws_size;

    const int node16Blk = (N_NODES + 15) / 16;   // 3125

    init_kernel<<<32, 256, 0, stream>>>((int*)sums, (int)(zeroBytes / 4), W2, w2t);
    bucket_scatter_kernel<<<EB, 256, 0, stream>>>(src, dst, bcnt, pairs);
    bucket_csr_kernel<<<NB, 256, 0, stream>>>(pairs, bcnt, csr, rowptr, cnt_node, dinv, x, xs);

    fused_l1_kernel<<<node16Blk, 256, 0, stream>>>(xs, csr, rowptr, cnt_node, dinv, W1, b1, bufA);
    fused_l2_kernel<<<node16Blk, 256, 0, stream>>>(bufA, csr, rowptr, cnt_node, dinv, w2t, b2,
                                                   bat, sums, cntg);
    head_kernel<<<1, 256, 0, stream>>>(sums, cntg, Wc, bc, out);
}